// Round 1
// baseline (344.214 us; speedup 1.0000x reference)
//
#include <hip/hip_runtime.h>

// ---------------------------------------------------------------------------
// MultiHeadAttention: B=2, S=2048, E=1024, H=16, D=64, causal mask.
//   qkv = x @ W_qkv + b_qkv ; split heads ; causal softmax attention ;
//   out = attn @ W_o + b_o
// Strategy: runtime dtype detection (harness may deliver fp32-or-bf16),
// canonicalize to bf16 in ws, then MFMA 16x16x32 bf16 everywhere (fp32 accum).
// ---------------------------------------------------------------------------

typedef __attribute__((ext_vector_type(8))) short short8;
typedef __attribute__((ext_vector_type(4))) float floatx4;

#define NB 2
#define SEQ 2048
#define EMB 1024
#define NH 16
#define HD 64
#define M_ROWS (NB * SEQ)        // 4096
#define N_QKV (3 * EMB)          // 3072

static __device__ __forceinline__ unsigned short f2bf(float f) {
    union { float f; unsigned int u; } v; v.f = f;
    unsigned int r = v.u + 0x7FFFu + ((v.u >> 16) & 1u);
    return (unsigned short)(r >> 16);
}
static __device__ __forceinline__ float bf2f(unsigned short h) {
    union { unsigned int u; float f; } v; v.u = ((unsigned int)h) << 16;
    return v.f;
}

// ---------------------------------------------------------------------------
// Dtype detection: x ~ N(0,1). If the buffer is bf16, even-indexed ushorts are
// bf16 samples (exponent field in [112,134] essentially always). If fp32,
// even-indexed ushorts are low mantissa bits (uniform -> ~9% in range).
// flag = 1 means "inputs/outputs are bf16".
// ---------------------------------------------------------------------------
__global__ void detect_dtype(const unsigned short* __restrict__ x, int* __restrict__ flag) {
    __shared__ int sh[256];
    int t = threadIdx.x;
    int cnt = 0;
    for (int i = 0; i < 16; ++i) {
        unsigned short u = x[(t * 16 + i) * 2];
        int e = (u >> 7) & 0xFF;
        if (e >= 112 && e <= 134) cnt++;
    }
    sh[t] = cnt;
    __syncthreads();
    for (int s = 128; s > 0; s >>= 1) {
        if (t < s) sh[t] += sh[t + s];
        __syncthreads();
    }
    if (t == 0) flag[0] = (sh[0] > 2048) ? 1 : 0;
}

// x -> canonical bf16 buffer (8 bytes / thread)
__global__ void norm_to_bf16(const void* __restrict__ in, unsigned short* __restrict__ out,
                             int n4, const int* __restrict__ flag) {
    int i = blockIdx.x * blockDim.x + threadIdx.x;
    if (i >= n4) return;
    if (*flag) {
        ((unsigned long long*)out)[i] = ((const unsigned long long*)in)[i];
    } else {
        float4 v = ((const float4*)in)[i];
        unsigned long long p = (unsigned long long)f2bf(v.x)
            | ((unsigned long long)f2bf(v.y) << 16)
            | ((unsigned long long)f2bf(v.z) << 32)
            | ((unsigned long long)f2bf(v.w) << 48);
        ((unsigned long long*)out)[i] = p;
    }
}

// W[R][C] -> Wt[C][R] bf16 (LDS-tiled transpose, 32x32 tiles, block (32,8))
__global__ void transpose_to_bf16(const void* __restrict__ in, unsigned short* __restrict__ out,
                                  int R, int C, const int* __restrict__ flag) {
    __shared__ unsigned short tile[32][33];
    int tx = threadIdx.x, ty = threadIdx.y;
    int c0 = blockIdx.x * 32, r0 = blockIdx.y * 32;
    bool isbf = (*flag != 0);
    #pragma unroll
    for (int j = 0; j < 4; ++j) {
        int r = r0 + ty + j * 8, c = c0 + tx;
        unsigned short v = isbf ? ((const unsigned short*)in)[(size_t)r * C + c]
                                : f2bf(((const float*)in)[(size_t)r * C + c]);
        tile[ty + j * 8][tx] = v;
    }
    __syncthreads();
    #pragma unroll
    for (int j = 0; j < 4; ++j)
        out[(size_t)(c0 + ty + j * 8) * R + r0 + tx] = tile[tx][ty + j * 8];
}

__global__ void norm_bias_f32(const void* __restrict__ in, float* __restrict__ out,
                              int n, const int* __restrict__ flag) {
    int i = blockIdx.x * blockDim.x + threadIdx.x;
    if (i >= n) return;
    out[i] = (*flag) ? bf2f(((const unsigned short*)in)[i]) : ((const float*)in)[i];
}

// ---------------------------------------------------------------------------
// QKV GEMM: C[4096][3072] = x_bf[4096][1024] @ Wt^T + b, scattered to Q/K/V
// [B,H,S,D] bf16. 128x128 tile, BK=32, 4 waves, 4x4 MFMA tiles per wave.
// LDS stride 40 (pad +8) keeps ds_read_b128 conflict-free.
// ---------------------------------------------------------------------------
#define LDT 40

__global__ __launch_bounds__(256) void qkv_gemm(
    const unsigned short* __restrict__ A,   // [4096][1024]
    const unsigned short* __restrict__ Bt,  // [3072][1024]  (W_qkv^T)
    const float* __restrict__ bias,         // [3072]
    unsigned short* __restrict__ qb, unsigned short* __restrict__ kb,
    unsigned short* __restrict__ vb)
{
    const int K = EMB;
    __shared__ __align__(16) unsigned short As[128 * LDT];
    __shared__ __align__(16) unsigned short Bs[128 * LDT];
    int t = threadIdx.x;
    int m0 = blockIdx.y * 128;
    int n0 = blockIdx.x * 128;
    int w = t >> 6, lane = t & 63, quad = lane >> 4, lcol = lane & 15;
    int wr = w >> 1, wc = w & 1;

    floatx4 zero = {0.f, 0.f, 0.f, 0.f};
    floatx4 acc[4][4];
    #pragma unroll
    for (int i = 0; i < 4; ++i)
        #pragma unroll
        for (int j = 0; j < 4; ++j) acc[i][j] = zero;

    int sr = t >> 1;
    int sc = (t & 1) << 4;
    const unsigned short* aG = A + (size_t)(m0 + sr) * K + sc;
    const unsigned short* bG = Bt + (size_t)(n0 + sr) * K + sc;

    for (int k0 = 0; k0 < K; k0 += 32) {
        __syncthreads();
        *(int4*)(&As[sr * LDT + sc])     = *(const int4*)(aG + k0);
        *(int4*)(&As[sr * LDT + sc + 8]) = *(const int4*)(aG + k0 + 8);
        *(int4*)(&Bs[sr * LDT + sc])     = *(const int4*)(bG + k0);
        *(int4*)(&Bs[sr * LDT + sc + 8]) = *(const int4*)(bG + k0 + 8);
        __syncthreads();
        short8 af[4], bfm[4];
        #pragma unroll
        for (int i = 0; i < 4; ++i)
            af[i] = *(const short8*)(&As[(wr * 64 + i * 16 + lcol) * LDT + quad * 8]);
        #pragma unroll
        for (int j = 0; j < 4; ++j)
            bfm[j] = *(const short8*)(&Bs[(wc * 64 + j * 16 + lcol) * LDT + quad * 8]);
        #pragma unroll
        for (int i = 0; i < 4; ++i)
            #pragma unroll
            for (int j = 0; j < 4; ++j)
                acc[i][j] = __builtin_amdgcn_mfma_f32_16x16x32_bf16(af[i], bfm[j], acc[i][j], 0, 0, 0);
    }

    // epilogue: C/D layout col=lane&15, row=quad*4+reg
    #pragma unroll
    for (int i = 0; i < 4; ++i) {
        int m = m0 + wr * 64 + i * 16 + quad * 4;   // + r
        int b = m >> 11, s = m & 2047;
        #pragma unroll
        for (int j = 0; j < 4; ++j) {
            int n = n0 + wc * 64 + j * 16 + lcol;
            int which = n >> 10;
            int e = n & 1023;
            int h = e >> 6, d = e & 63;
            float bv = bias[n];
            unsigned short* dst = (which == 0) ? qb : ((which == 1) ? kb : vb);
            size_t base = ((size_t)((b * NH + h) * SEQ + s)) * HD + d;
            #pragma unroll
            for (int r = 0; r < 4; ++r)
                dst[base + (size_t)r * HD] = f2bf(acc[i][j][r] + bv);
        }
    }
}

// ---------------------------------------------------------------------------
// Flash attention, causal. Block = (qtile 64 rows) x (b,h). 4 waves, each owns
// 16 query rows. QK^T and PV via MFMA; P re-laid-out through per-wave LDS.
// ---------------------------------------------------------------------------
__global__ __launch_bounds__(256) void attn_kernel(
    const unsigned short* __restrict__ Q,   // [B*H][S][D]
    const unsigned short* __restrict__ Kk,
    const unsigned short* __restrict__ V,
    unsigned short* __restrict__ Out)       // [b][s][h*64+d]
{
    __shared__ __align__(16) unsigned short Qs[64 * 72];
    __shared__ __align__(16) unsigned short Ks[64 * 72];
    __shared__ __align__(16) unsigned short Vt[64 * 72];   // [d][key]
    __shared__ __align__(16) unsigned short Ps[4][16 * 72];

    int qt = blockIdx.x;
    int bh = blockIdx.y;
    int q0 = qt * 64;
    int t = threadIdx.x;
    int w = t >> 6, lane = t & 63, quad = lane >> 4, lcol = lane & 15;
    const size_t head_off = (size_t)bh * SEQ * HD;

    {   // stage Q tile once
        int r = t >> 2, c = (t & 3) << 4;
        const unsigned short* src = Q + head_off + (size_t)(q0 + r) * HD + c;
        *(int4*)(&Qs[r * 72 + c])     = *(const int4*)(src);
        *(int4*)(&Qs[r * 72 + c + 8]) = *(const int4*)(src + 8);
    }

    floatx4 zero = {0.f, 0.f, 0.f, 0.f};
    float m_i[4], l_i[4];
    floatx4 O[4];
    #pragma unroll
    for (int r = 0; r < 4; ++r) { m_i[r] = -3.0e38f; l_i[r] = 0.f; }
    #pragma unroll
    for (int d = 0; d < 4; ++d) O[d] = zero;

    for (int kt = 0; kt <= qt; ++kt) {
        int k0 = kt * 64;
        __syncthreads();
        {   // stage K tile + V tile (transposed)
            int r = t >> 2, c = (t & 3) << 4;
            const unsigned short* ksrc = Kk + head_off + (size_t)(k0 + r) * HD + c;
            *(int4*)(&Ks[r * 72 + c])     = *(const int4*)(ksrc);
            *(int4*)(&Ks[r * 72 + c + 8]) = *(const int4*)(ksrc + 8);
            const unsigned short* vsrc = V + head_off + (size_t)(k0 + r) * HD + c;
            unsigned short tmp[16];
            *(int4*)(&tmp[0]) = *(const int4*)(vsrc);
            *(int4*)(&tmp[8]) = *(const int4*)(vsrc + 8);
            #pragma unroll
            for (int j = 0; j < 16; ++j)
                Vt[(c + j) * 72 + r] = tmp[j];
        }
        __syncthreads();

        // S = Q K^T  (m=q row, n=key)
        floatx4 sacc[4];
        #pragma unroll
        for (int j = 0; j < 4; ++j) sacc[j] = zero;
        short8 aq0 = *(const short8*)(&Qs[(16 * w + lcol) * 72 + quad * 8]);
        short8 aq1 = *(const short8*)(&Qs[(16 * w + lcol) * 72 + 32 + quad * 8]);
        #pragma unroll
        for (int tc = 0; tc < 4; ++tc) {
            short8 bk0 = *(const short8*)(&Ks[(tc * 16 + lcol) * 72 + quad * 8]);
            short8 bk1 = *(const short8*)(&Ks[(tc * 16 + lcol) * 72 + 32 + quad * 8]);
            sacc[tc] = __builtin_amdgcn_mfma_f32_16x16x32_bf16(aq0, bk0, sacc[tc], 0, 0, 0);
            sacc[tc] = __builtin_amdgcn_mfma_f32_16x16x32_bf16(aq1, bk1, sacc[tc], 0, 0, 0);
        }

        bool diag = (kt == qt);
        float sv[4][4];
        float mloc[4] = {-3.0e38f, -3.0e38f, -3.0e38f, -3.0e38f};
        #pragma unroll
        for (int tc = 0; tc < 4; ++tc) {
            int key = k0 + tc * 16 + lcol;
            #pragma unroll
            for (int r = 0; r < 4; ++r) {
                float s = sacc[tc][r] * 0.125f;
                int qrow = q0 + 16 * w + quad * 4 + r;
                if (diag && key > qrow) s = -3.0e38f;
                sv[tc][r] = s;
                mloc[r] = fmaxf(mloc[r], s);
            }
        }
        #pragma unroll
        for (int r = 0; r < 4; ++r) {
            #pragma unroll
            for (int off = 1; off < 16; off <<= 1)
                mloc[r] = fmaxf(mloc[r], __shfl_xor(mloc[r], off, 64));
        }
        float alpha[4], psum[4];
        #pragma unroll
        for (int r = 0; r < 4; ++r) {
            float mn = fmaxf(m_i[r], mloc[r]);
            alpha[r] = __expf(m_i[r] - mn);
            m_i[r] = mn;
            psum[r] = 0.f;
        }
        #pragma unroll
        for (int tc = 0; tc < 4; ++tc) {
            #pragma unroll
            for (int r = 0; r < 4; ++r) {
                float p = __expf(sv[tc][r] - m_i[r]);
                psum[r] += p;
                Ps[w][(quad * 4 + r) * 72 + tc * 16 + lcol] = f2bf(p);
            }
        }
        #pragma unroll
        for (int r = 0; r < 4; ++r) {
            #pragma unroll
            for (int off = 1; off < 16; off <<= 1)
                psum[r] += __shfl_xor(psum[r], off, 64);
            l_i[r] = l_i[r] * alpha[r] + psum[r];
        }
        #pragma unroll
        for (int d = 0; d < 4; ++d) {
            #pragma unroll
            for (int r = 0; r < 4; ++r) O[d][r] *= alpha[r];
        }

        // O += P @ V  (A = P strip from LDS, B = Vt rows)
        short8 ap0 = *(const short8*)(&Ps[w][lcol * 72 + quad * 8]);
        short8 ap1 = *(const short8*)(&Ps[w][lcol * 72 + 32 + quad * 8]);
        #pragma unroll
        for (int td = 0; td < 4; ++td) {
            short8 bv0 = *(const short8*)(&Vt[(td * 16 + lcol) * 72 + quad * 8]);
            short8 bv1 = *(const short8*)(&Vt[(td * 16 + lcol) * 72 + 32 + quad * 8]);
            O[td] = __builtin_amdgcn_mfma_f32_16x16x32_bf16(ap0, bv0, O[td], 0, 0, 0);
            O[td] = __builtin_amdgcn_mfma_f32_16x16x32_bf16(ap1, bv1, O[td], 0, 0, 0);
        }
    }

    int b = bh >> 4, h = bh & 15;
    float inv[4];
    #pragma unroll
    for (int r = 0; r < 4; ++r) inv[r] = 1.0f / l_i[r];
    size_t obase = ((size_t)b * SEQ) * EMB + (size_t)h * HD;
    #pragma unroll
    for (int td = 0; td < 4; ++td) {
        #pragma unroll
        for (int r = 0; r < 4; ++r) {
            int qrow = q0 + 16 * w + quad * 4 + r;
            Out[obase + (size_t)qrow * EMB + td * 16 + lcol] = f2bf(O[td][r] * inv[r]);
        }
    }
}

// ---------------------------------------------------------------------------
// Output projection: out[4096][1024] = attn @ W_o + b_o (fp32 or bf16 store)
// ---------------------------------------------------------------------------
__global__ __launch_bounds__(256) void oproj_gemm(
    const unsigned short* __restrict__ A,   // [4096][1024]
    const unsigned short* __restrict__ Bt,  // [1024][1024]  (W_o^T)
    const float* __restrict__ bias,         // [1024]
    void* __restrict__ Cout,
    const int* __restrict__ flag)
{
    const int K = EMB;
    __shared__ __align__(16) unsigned short As[128 * LDT];
    __shared__ __align__(16) unsigned short Bs[128 * LDT];
    int t = threadIdx.x;
    int m0 = blockIdx.y * 128;
    int n0 = blockIdx.x * 128;
    int w = t >> 6, lane = t & 63, quad = lane >> 4, lcol = lane & 15;
    int wr = w >> 1, wc = w & 1;

    floatx4 zero = {0.f, 0.f, 0.f, 0.f};
    floatx4 acc[4][4];
    #pragma unroll
    for (int i = 0; i < 4; ++i)
        #pragma unroll
        for (int j = 0; j < 4; ++j) acc[i][j] = zero;

    int sr = t >> 1;
    int sc = (t & 1) << 4;
    const unsigned short* aG = A + (size_t)(m0 + sr) * K + sc;
    const unsigned short* bG = Bt + (size_t)(n0 + sr) * K + sc;

    for (int k0 = 0; k0 < K; k0 += 32) {
        __syncthreads();
        *(int4*)(&As[sr * LDT + sc])     = *(const int4*)(aG + k0);
        *(int4*)(&As[sr * LDT + sc + 8]) = *(const int4*)(aG + k0 + 8);
        *(int4*)(&Bs[sr * LDT + sc])     = *(const int4*)(bG + k0);
        *(int4*)(&Bs[sr * LDT + sc + 8]) = *(const int4*)(bG + k0 + 8);
        __syncthreads();
        short8 af[4], bfm[4];
        #pragma unroll
        for (int i = 0; i < 4; ++i)
            af[i] = *(const short8*)(&As[(wr * 64 + i * 16 + lcol) * LDT + quad * 8]);
        #pragma unroll
        for (int j = 0; j < 4; ++j)
            bfm[j] = *(const short8*)(&Bs[(wc * 64 + j * 16 + lcol) * LDT + quad * 8]);
        #pragma unroll
        for (int i = 0; i < 4; ++i)
            #pragma unroll
            for (int j = 0; j < 4; ++j)
                acc[i][j] = __builtin_amdgcn_mfma_f32_16x16x32_bf16(af[i], bfm[j], acc[i][j], 0, 0, 0);
    }

    bool isbf = (*flag != 0);
    #pragma unroll
    for (int i = 0; i < 4; ++i) {
        int m = m0 + wr * 64 + i * 16 + quad * 4;
        #pragma unroll
        for (int j = 0; j < 4; ++j) {
            int n = n0 + wc * 64 + j * 16 + lcol;
            float bv = bias[n];
            #pragma unroll
            for (int r = 0; r < 4; ++r) {
                float v = acc[i][j][r] + bv;
                size_t idx = (size_t)(m + r) * EMB + n;
                if (isbf) ((unsigned short*)Cout)[idx] = f2bf(v);
                else      ((float*)Cout)[idx] = v;
            }
        }
    }
}

// ---------------------------------------------------------------------------
extern "C" void kernel_launch(void* const* d_in, const int* in_sizes, int n_in,
                              void* d_out, int out_size, void* d_ws, size_t ws_size,
                              hipStream_t stream) {
    (void)in_sizes; (void)n_in; (void)out_size; (void)ws_size;
    char* ws = (char*)d_ws;
    // workspace layout (all 1024B aligned), total ~48.0 MB
    const size_t OFF_X     = 1024;
    const size_t OFF_WQKVT = OFF_X     + (size_t)M_ROWS * EMB * 2;      // +8 MB
    const size_t OFF_WOT   = OFF_WQKVT + (size_t)N_QKV * EMB * 2;       // +6 MB
    const size_t OFF_BQKV  = OFF_WOT   + (size_t)EMB * EMB * 2;         // +2 MB
    const size_t OFF_BO    = OFF_BQKV  + 16384;
    const size_t OFF_Q     = OFF_BO    + 16384;
    const size_t OFF_K     = OFF_Q     + (size_t)M_ROWS * EMB * 2;
    const size_t OFF_V     = OFF_K     + (size_t)M_ROWS * EMB * 2;
    const size_t OFF_ATTN  = OFF_V     + (size_t)M_ROWS * EMB * 2;

    int* flag = (int*)ws;
    unsigned short* x_bf   = (unsigned short*)(ws + OFF_X);
    unsigned short* wqkvT  = (unsigned short*)(ws + OFF_WQKVT);
    unsigned short* woT    = (unsigned short*)(ws + OFF_WOT);
    float*          bqkv_f = (float*)(ws + OFF_BQKV);
    float*          bo_f   = (float*)(ws + OFF_BO);
    unsigned short* qb     = (unsigned short*)(ws + OFF_Q);
    unsigned short* kb     = (unsigned short*)(ws + OFF_K);
    unsigned short* vb     = (unsigned short*)(ws + OFF_V);
    unsigned short* attn   = (unsigned short*)(ws + OFF_ATTN);

    detect_dtype<<<1, 256, 0, stream>>>((const unsigned short*)d_in[0], flag);
    norm_to_bf16<<<(M_ROWS * EMB / 4 + 255) / 256, 256, 0, stream>>>(d_in[0], x_bf, M_ROWS * EMB / 4, flag);
    transpose_to_bf16<<<dim3(N_QKV / 32, EMB / 32), dim3(32, 8), 0, stream>>>(d_in[1], wqkvT, EMB, N_QKV, flag);
    transpose_to_bf16<<<dim3(EMB / 32, EMB / 32), dim3(32, 8), 0, stream>>>(d_in[3], woT, EMB, EMB, flag);
    norm_bias_f32<<<(N_QKV + 255) / 256, 256, 0, stream>>>(d_in[2], bqkv_f, N_QKV, flag);
    norm_bias_f32<<<(EMB + 255) / 256, 256, 0, stream>>>(d_in[4], bo_f, EMB, flag);

    qkv_gemm<<<dim3(N_QKV / 128, M_ROWS / 128), 256, 0, stream>>>(x_bf, wqkvT, bqkv_f, qb, kb, vb);
    attn_kernel<<<dim3(SEQ / 64, NB * NH), 256, 0, stream>>>(qb, kb, vb, attn);
    oproj_gemm<<<dim3(EMB / 128, M_ROWS / 128), 256, 0, stream>>>(attn, woT, bo_f, d_out, flag);
}